// Round 6
// baseline (273.015 us; speedup 1.0000x reference)
//
#include <hip/hip_runtime.h>
#include <math.h>

#define BATCH 32
#define NTOK 577
#define NPATCH 576
#define CDIM 768
#define HEADS 12
#define DHEAD 64
#define W3 2304
#define FT 404

// ---- workspace layout (float offsets) ----
#define WS_WTIL  24576      // 32*12*768         -> 319488
#define WS_DBIAS 319488     // 32*12             -> 319872
#define WS_DOTS  319872     // 32*12*577         -> 541440
#define WS_IND   541440     // 32*404 (as int)   -> 554368

// ---- output layout (float offsets) ----
#define O_X      0ULL
#define O_INDEX  14180352ULL
#define O_IND    24109056ULL
#define O_CA     24121984ULL
#define O_FT     24140416ULL

#define NIDX4  2482176   // 32*404*768/4  float4 of index broadcast
#define NCOPY4 3545088   // 32*577*768/4  float4 of x->out copy

// K_fold: unchanged.
__global__ __launch_bounds__(512) void k_fold(const float* __restrict__ x,
                                              const float* __restrict__ W,
                                              const float* __restrict__ bq,
                                              float* __restrict__ wtil,
                                              float* __restrict__ dbias) {
    __shared__ float x0s[CDIM];
    __shared__ float red[512];
    __shared__ float qs[DHEAD];
    const int b = blockIdx.x, h = blockIdx.y, tid = threadIdx.x;
    if (tid < CDIM / 4)
        ((float4*)x0s)[tid] = ((const float4*)(x + (size_t)b * NTOK * CDIM))[tid];
    __syncthreads();
    {
        const int d = tid & 63, seg = tid >> 6;
        const float* Wq = W + h * DHEAD + d;
        const int c0 = seg * 96;
        float acc = 0.f;
        #pragma unroll 32
        for (int c = c0; c < c0 + 96; c++) acc += x0s[c] * Wq[(size_t)c * W3];
        red[tid] = acc;
    }
    __syncthreads();
    if (tid < DHEAD) {
        float q = red[tid];
        #pragma unroll
        for (int s = 1; s < 8; s++) q += red[tid + s * 64];
        q += bq[h * DHEAD + tid];
        qs[tid] = q;
        float t = q * bq[CDIM + h * DHEAD + tid];
        #pragma unroll
        for (int off = 32; off; off >>= 1) t += __shfl_down(t, off);
        if (tid == 0) dbias[b * HEADS + h] = t;
    }
    __syncthreads();
    for (int c = tid; c < CDIM; c += 512) {
        const float* wr = W + (size_t)c * W3 + CDIM + h * DHEAD;
        float acc = 0.f;
        #pragma unroll
        for (int d = 0; d < DHEAD; d += 4) {
            float4 a = *reinterpret_cast<const float4*>(wr + d);
            acc += a.x * qs[d] + a.y * qs[d + 1] + a.z * qs[d + 2] + a.w * qs[d + 3];
        }
        wtil[((size_t)b * HEADS + h) * CDIM + c] = acc;
    }
}

// K_dots: SAME logic as round 5, wrapped in REP=3 diagnostic loop. Pointers
// offset by an asm-opaque runtime zero so reps can't be hoisted or DSE'd;
// stores are idempotent -> outputs bit-identical.
#define LOADG(A, G)                                                               \
    {                                                                             \
        _Pragma("unroll")                                                         \
        for (int u = 0; u < 4; u++) {                                             \
            const int j = jbase + (G) * 4 + u;                                    \
            if (j < NTOK) {                                                       \
                const float4* xp =                                                \
                    (const float4*)(xL + ((size_t)b * NTOK + j) * CDIM);          \
                A[u][0] = xp[lane]; A[u][1] = xp[64 + lane]; A[u][2] = xp[128 + lane]; \
            } else {                                                              \
                A[u][0] = A[u][1] = A[u][2] = make_float4(0.f, 0.f, 0.f, 0.f);    \
            }                                                                     \
        }                                                                         \
    }

#define COMPG(A, G)                                                               \
    {                                                                             \
        float acc[4][3];                                                          \
        _Pragma("unroll")                                                         \
        for (int u = 0; u < 4; u++) { acc[u][0] = acc[u][1] = acc[u][2] = 0.f; }  \
        _Pragma("unroll")                                                         \
        for (int i = 0; i < 3; i++)                                               \
            _Pragma("unroll")                                                     \
            for (int u = 0; u < 4; u++)                                           \
                _Pragma("unroll")                                                 \
                for (int hh = 0; hh < 3; hh++)                                    \
                    acc[u][hh] += A[u][i].x * wr[hh][i].x + A[u][i].y * wr[hh][i].y \
                                + A[u][i].z * wr[hh][i].z + A[u][i].w * wr[hh][i].w; \
        _Pragma("unroll")                                                         \
        for (int off = 32; off; off >>= 1)                                        \
            _Pragma("unroll")                                                     \
            for (int u = 0; u < 4; u++)                                           \
                _Pragma("unroll")                                                 \
                for (int hh = 0; hh < 3; hh++)                                    \
                    acc[u][hh] += __shfl_xor(acc[u][hh], off);                    \
        if (lane == 0) {                                                          \
            _Pragma("unroll")                                                     \
            for (int u = 0; u < 4; u++) {                                         \
                const int j = jbase + (G) * 4 + u;                                \
                if (j < NTOK) {                                                   \
                    _Pragma("unroll")                                             \
                    for (int hh = 0; hh < 3; hh++)                                \
                        dotsL[((size_t)b * HEADS + h0 + hh) * NTOK + j] =         \
                            0.125f * (acc[u][hh] + db[hh]);                       \
                }                                                                 \
            }                                                                     \
        }                                                                         \
    }

__global__ __launch_bounds__(256, 3) void k_dots(const float* __restrict__ x,
                                                 const float* __restrict__ wtil,
                                                 const float* __restrict__ dbias,
                                                 float* __restrict__ dots) {
    const int b = blockIdx.x, tid = threadIdx.x;
    const int w = tid >> 6, lane = tid & 63, h0 = w * 3;
    const int jbase = blockIdx.y * 16;
    for (int rep = 0; rep < 3; ++rep) {
        int z = 0;
        asm volatile("" : "+v"(z));          // runtime zero, opaque to compiler
        const float* xL    = x + z;
        const float* wtL   = wtil + z;
        const float* dbL   = dbias + z;
        float*       dotsL = dots + z;
        float4 wr[3][3];
        float db[3];
        #pragma unroll
        for (int hh = 0; hh < 3; hh++) {
            #pragma unroll
            for (int i = 0; i < 3; i++)
                wr[hh][i] = *reinterpret_cast<const float4*>(
                    wtL + ((size_t)b * HEADS + h0 + hh) * CDIM + i * 256 + lane * 4);
            db[hh] = dbL[b * HEADS + h0 + hh];
        }
        float4 abuf[4][3], nbuf[4][3];
        LOADG(abuf, 0);
        LOADG(nbuf, 1);
        COMPG(abuf, 0);
        LOADG(abuf, 2);
        COMPG(nbuf, 1);
        LOADG(nbuf, 3);
        COMPG(abuf, 2);
        COMPG(nbuf, 3);
    }
}

// K_catopk: unchanged.
__global__ __launch_bounds__(512) void k_catopk(const float* __restrict__ dots,
                                                float* __restrict__ out,
                                                int* __restrict__ indws,
                                                int write_ft) {
    __shared__ float dl[HEADS * NTOK];        // 27.7 KB
    __shared__ float mh[HEADS], sh[HEADS];
    __shared__ unsigned vals[NPATCH];
    __shared__ unsigned long long segmask[9];
    __shared__ int segoff[9];
    const int b = blockIdx.x, tid = threadIdx.x;
    {
        const float4* s4 = (const float4*)(dots + (size_t)b * HEADS * NTOK);
        float4* d4 = (float4*)dl;
        for (int i = tid; i < HEADS * NTOK / 4; i += 512) d4[i] = s4[i];   // 1731 float4
    }
    __syncthreads();
    const int w = tid >> 6, lane = tid & 63;
    for (int h = w; h < HEADS; h += 8) {
        const float* row = dl + h * NTOK;
        float m = -3.4e38f;
        for (int j = lane; j < NTOK; j += 64) m = fmaxf(m, row[j]);
        #pragma unroll
        for (int off = 32; off; off >>= 1) m = fmaxf(m, __shfl_xor(m, off));
        float s = 0.f;
        for (int j = lane; j < NTOK; j += 64) s += expf(row[j] - m);
        #pragma unroll
        for (int off = 32; off; off >>= 1) s += __shfl_xor(s, off);
        if (lane == 0) { mh[h] = m; sh[h] = s; }
    }
    __syncthreads();
    for (int t = tid; t < NPATCH; t += 512) {
        float ca = 0.f;
        #pragma unroll
        for (int h = 0; h < HEADS; h++)
            ca += expf(dl[h * NTOK + 1 + t] - mh[h]) / sh[h];
        ca *= (1.f / 12.f);
        out[O_CA + (size_t)b * NPATCH + t] = ca;
        vals[t] = __float_as_uint(ca);   // ca > 0 -> bit order == value order
    }
    __syncthreads();
    {
        const uint4* v4 = (const uint4*)vals;
        for (int s = w; s < 9; s += 8) {
            const int t = s * 64 + lane;
            const unsigned myv = vals[t];
            int rank = 0;
            #pragma unroll 8
            for (int j4 = 0; j4 < NPATCH / 4; j4++) {
                const uint4 vv = v4[j4];
                const int j = j4 * 4;
                rank += (vv.x > myv) || (vv.x == myv && j     < t);
                rank += (vv.y > myv) || (vv.y == myv && j + 1 < t);
                rank += (vv.z > myv) || (vv.z == myv && j + 2 < t);
                rank += (vv.w > myv) || (vv.w == myv && j + 3 < t);
            }
            const unsigned long long mask = __ballot(rank < FT);
            if (lane == 0) segmask[s] = mask;
        }
    }
    __syncthreads();
    if (tid == 0) {
        int acc = 0;
        #pragma unroll
        for (int s = 0; s < 9; s++) { segoff[s] = acc; acc += __popcll(segmask[s]); }
    }
    __syncthreads();
    for (int s = w; s < 9; s += 8) {
        const int t = s * 64 + lane;
        const unsigned long long mask = segmask[s];
        if ((mask >> lane) & 1ull) {
            const int pos = segoff[s] + __popcll(mask & ((1ull << lane) - 1ull));
            indws[b * FT + pos] = t;
            out[O_IND + (size_t)b * FT + pos] = (float)t;
        }
    }
    if (b == 0 && tid == 0 && write_ft) out[O_FT] = (float)FT;
}

// K_bcast: unchanged.
__global__ __launch_bounds__(256) void k_bcast(const int* __restrict__ ind,
                                               const float* __restrict__ x,
                                               float* __restrict__ out) {
    const float4* x4 = (const float4*)x;
    float4* o4 = (float4*)(out + O_X);
    float4* i4 = (float4*)(out + O_INDEX);
    const unsigned stride = gridDim.x * 256u;
    for (unsigned g = blockIdx.x * 256u + threadIdx.x; g < NIDX4 + NCOPY4; g += stride) {
        if (g < NCOPY4) {
            o4[g] = x4[g];
        } else {
            const unsigned e = g - NCOPY4;
            const unsigned row = e / 192u;       // 192 float4 per 768-float row
            const float v = (float)ind[row];
            float4 o; o.x = v; o.y = v; o.z = v; o.w = v;
            i4[e] = o;
        }
    }
}

extern "C" void kernel_launch(void* const* d_in, const int* in_sizes, int n_in,
                              void* d_out, int out_size, void* d_ws, size_t ws_size,
                              hipStream_t stream) {
    const float* x  = (const float*)d_in[0];
    const float* W  = (const float*)d_in[2];   // W_qkv [768, 2304]
    const float* bq = (const float*)d_in[3];   // b_qkv [2304]
    float* ws = (float*)d_ws;
    float* out = (float*)d_out;

    k_fold<<<dim3(BATCH, HEADS), 512, 0, stream>>>(x, W, bq, ws + WS_WTIL, ws + WS_DBIAS);
    k_dots<<<dim3(BATCH, 37), 256, 0, stream>>>(x, ws + WS_WTIL, ws + WS_DBIAS,
                                                ws + WS_DOTS);
    const int write_ft = (out_size > (int)O_FT) ? 1 : 0;
    k_catopk<<<BATCH, 512, 0, stream>>>(ws + WS_DOTS, out, (int*)(ws + WS_IND), write_ft);
    k_bcast<<<2048, 256, 0, stream>>>((const int*)(ws + WS_IND), x, out);
}

// Round 7
// 251.910 us; speedup vs baseline: 1.0838x; 1.0838x over previous
//
#include <hip/hip_runtime.h>
#include <math.h>

#define BATCH 32
#define NTOK 577
#define NPATCH 576
#define CDIM 768
#define HEADS 12
#define DHEAD 64
#define W3 2304
#define FT 404

// ---- workspace layout (float offsets) ----
#define WS_WTIL  24576      // 32*12*768         -> 319488
#define WS_DBIAS 319488     // 32*12             -> 319872
#define WS_DOTS  319872     // 32*12*577         -> 541440
#define WS_IND   541440     // 32*404 (as int)   -> 554368

// ---- output layout (float offsets) ----
#define O_X      0ULL
#define O_INDEX  14180352ULL
#define O_IND    24109056ULL
#define O_CA     24121984ULL
#define O_FT     24140416ULL

#define NIDX4  2482176   // 32*404*768/4  float4 of index broadcast
#define NCOPY4 3545088   // 32*577*768/4  float4 of x->out copy

#define XROW 132         // LDS row stride (floats): 16B-aligned, bank-balanced

// K_fold: unchanged (next round's target; measuring by subtraction this round).
__global__ __launch_bounds__(512) void k_fold(const float* __restrict__ x,
                                              const float* __restrict__ W,
                                              const float* __restrict__ bq,
                                              float* __restrict__ wtil,
                                              float* __restrict__ dbias) {
    __shared__ float x0s[CDIM];
    __shared__ float red[512];
    __shared__ float qs[DHEAD];
    const int b = blockIdx.x, h = blockIdx.y, tid = threadIdx.x;
    if (tid < CDIM / 4)
        ((float4*)x0s)[tid] = ((const float4*)(x + (size_t)b * NTOK * CDIM))[tid];
    __syncthreads();
    {
        const int d = tid & 63, seg = tid >> 6;
        const float* Wq = W + h * DHEAD + d;
        const int c0 = seg * 96;
        float acc = 0.f;
        #pragma unroll 32
        for (int c = c0; c < c0 + 96; c++) acc += x0s[c] * Wq[(size_t)c * W3];
        red[tid] = acc;
    }
    __syncthreads();
    if (tid < DHEAD) {
        float q = red[tid];
        #pragma unroll
        for (int s = 1; s < 8; s++) q += red[tid + s * 64];
        q += bq[h * DHEAD + tid];
        qs[tid] = q;
        float t = q * bq[CDIM + h * DHEAD + tid];
        #pragma unroll
        for (int off = 32; off; off >>= 1) t += __shfl_down(t, off);
        if (tid == 0) dbias[b * HEADS + h] = t;
    }
    __syncthreads();
    for (int c = tid; c < CDIM; c += 512) {
        const float* wr = W + (size_t)c * W3 + CDIM + h * DHEAD;
        float acc = 0.f;
        #pragma unroll
        for (int d = 0; d < DHEAD; d += 4) {
            float4 a = *reinterpret_cast<const float4*>(wr + d);
            acc += a.x * qs[d] + a.y * qs[d + 1] + a.z * qs[d + 2] + a.w * qs[d + 3];
        }
        wtil[((size_t)b * HEADS + h) * CDIM + c] = acc;
    }
}

// K_dots v5: register-blocked, LDS-staged, butterfly-ectomy.
// Grid (32 b, 10): block covers 64-token j-tile. Thread (jq=tid&15, cs=tid>>4)
// owns rows {jq, jq+16, jq+32, jq+48} x all 12 heads x 8-c slice per 128-c
// chunk: 384 FMA per 16 LDS b128 reads. Final reduce: 2 shfl levels (cs within
// wave) + 12KB LDS cross-wave reduce. No per-row butterflies.
__global__ __launch_bounds__(256) void k_dots(const float* __restrict__ x,
                                              const float* __restrict__ wtil,
                                              const float* __restrict__ dbias,
                                              float* __restrict__ dots) {
    __shared__ __align__(16) float smem[64 * XROW + HEADS * CDIM];  // 70.7 KB
    float* const xt = smem;                 // [64][XROW]
    float* const wt = smem + 64 * XROW;     // [12][768]
    float* const part = smem;               // 3072 floats, aliases xt (used after)
    const int b = blockIdx.x, y = blockIdx.y, tid = threadIdx.x;
    const int j0 = y * 64;
    const int jq = tid & 15, cs = tid >> 4;
    const int w = tid >> 6, lane = tid & 63;
    // stage wt (12x768 = 2304 float4)
    {
        const float4* s4 = (const float4*)(wtil + (size_t)b * HEADS * CDIM);
        float4* d4 = (float4*)wt;
        #pragma unroll
        for (int i = 0; i < 9; i++) d4[tid + i * 256] = s4[tid + i * 256];
    }
    float acc[4][12];
    #pragma unroll
    for (int r = 0; r < 4; r++)
        #pragma unroll
        for (int h = 0; h < 12; h++) acc[r][h] = 0.f;
    const float4* xg = (const float4*)x;
    for (int k = 0; k < 6; k++) {
        __syncthreads();   // k=0: wt staged; k>0: xt consumed by prev compute
        #pragma unroll
        for (int i = 0; i < 8; i++) {
            const int f = tid + i * 256;
            const int row = f >> 5, col = f & 31;
            float4 v = make_float4(0.f, 0.f, 0.f, 0.f);
            if (j0 + row < NTOK)
                v = xg[(size_t)(b * NTOK + j0 + row) * 192 + k * 32 + col];
            *(float4*)&xt[row * XROW + col * 4] = v;
        }
        __syncthreads();
        #pragma unroll
        for (int f = 0; f < 2; f++) {
            const int col4 = cs * 2 + f;
            float4 xa[4];
            #pragma unroll
            for (int r = 0; r < 4; r++)
                xa[r] = *(const float4*)&xt[(jq + 16 * r) * XROW + col4 * 4];
            #pragma unroll
            for (int h = 0; h < 12; h++) {
                const float4 wv = *(const float4*)&wt[h * CDIM + k * 128 + col4 * 4];
                #pragma unroll
                for (int r = 0; r < 4; r++)
                    acc[r][h] += xa[r].x * wv.x + xa[r].y * wv.y
                               + xa[r].z * wv.z + xa[r].w * wv.w;
            }
        }
    }
    // reduce the wave's 4 csegs: lanes l, l^16 (cs^1), l^32 (cs^2)
    #pragma unroll
    for (int off = 16; off <= 32; off <<= 1)
        #pragma unroll
        for (int r = 0; r < 4; r++)
            #pragma unroll
            for (int h = 0; h < 12; h++)
                acc[r][h] += __shfl_xor(acc[r][h], off);
    __syncthreads();   // xt reads done before part overwrites it
    if (lane < 16) {   // one writer per (wave, jq): lane == jq
        #pragma unroll
        for (int r = 0; r < 4; r++)
            #pragma unroll
            for (int h = 0; h < 12; h++)
                part[w * 768 + lane * 48 + r * 12 + h] = acc[r][h];
    }
    __syncthreads();
    #pragma unroll
    for (int s = 0; s < 3; s++) {
        const int o = tid + s * 256;                 // o in [0,768)
        const int jq2 = o / 48, rh = o - jq2 * 48;
        const int r = rh / 12, h = rh - r * 12;
        const int j = j0 + jq2 + 16 * r;
        if (j < NTOK) {
            const float sum = part[o] + part[768 + o] + part[1536 + o] + part[2304 + o];
            dots[((size_t)b * HEADS + h) * NTOK + j] =
                0.125f * (sum + dbias[b * HEADS + h]);
        }
    }
}

// K_catopk: unchanged.
__global__ __launch_bounds__(512) void k_catopk(const float* __restrict__ dots,
                                                float* __restrict__ out,
                                                int* __restrict__ indws,
                                                int write_ft) {
    __shared__ float dl[HEADS * NTOK];        // 27.7 KB
    __shared__ float mh[HEADS], sh[HEADS];
    __shared__ unsigned vals[NPATCH];
    __shared__ unsigned long long segmask[9];
    __shared__ int segoff[9];
    const int b = blockIdx.x, tid = threadIdx.x;
    {
        const float4* s4 = (const float4*)(dots + (size_t)b * HEADS * NTOK);
        float4* d4 = (float4*)dl;
        for (int i = tid; i < HEADS * NTOK / 4; i += 512) d4[i] = s4[i];   // 1731 float4
    }
    __syncthreads();
    const int w = tid >> 6, lane = tid & 63;
    for (int h = w; h < HEADS; h += 8) {
        const float* row = dl + h * NTOK;
        float m = -3.4e38f;
        for (int j = lane; j < NTOK; j += 64) m = fmaxf(m, row[j]);
        #pragma unroll
        for (int off = 32; off; off >>= 1) m = fmaxf(m, __shfl_xor(m, off));
        float s = 0.f;
        for (int j = lane; j < NTOK; j += 64) s += expf(row[j] - m);
        #pragma unroll
        for (int off = 32; off; off >>= 1) s += __shfl_xor(s, off);
        if (lane == 0) { mh[h] = m; sh[h] = s; }
    }
    __syncthreads();
    for (int t = tid; t < NPATCH; t += 512) {
        float ca = 0.f;
        #pragma unroll
        for (int h = 0; h < HEADS; h++)
            ca += expf(dl[h * NTOK + 1 + t] - mh[h]) / sh[h];
        ca *= (1.f / 12.f);
        out[O_CA + (size_t)b * NPATCH + t] = ca;
        vals[t] = __float_as_uint(ca);   // ca > 0 -> bit order == value order
    }
    __syncthreads();
    {
        const uint4* v4 = (const uint4*)vals;
        for (int s = w; s < 9; s += 8) {
            const int t = s * 64 + lane;
            const unsigned myv = vals[t];
            int rank = 0;
            #pragma unroll 8
            for (int j4 = 0; j4 < NPATCH / 4; j4++) {
                const uint4 vv = v4[j4];
                const int j = j4 * 4;
                rank += (vv.x > myv) || (vv.x == myv && j     < t);
                rank += (vv.y > myv) || (vv.y == myv && j + 1 < t);
                rank += (vv.z > myv) || (vv.z == myv && j + 2 < t);
                rank += (vv.w > myv) || (vv.w == myv && j + 3 < t);
            }
            const unsigned long long mask = __ballot(rank < FT);
            if (lane == 0) segmask[s] = mask;
        }
    }
    __syncthreads();
    if (tid == 0) {
        int acc = 0;
        #pragma unroll
        for (int s = 0; s < 9; s++) { segoff[s] = acc; acc += __popcll(segmask[s]); }
    }
    __syncthreads();
    for (int s = w; s < 9; s += 8) {
        const int t = s * 64 + lane;
        const unsigned long long mask = segmask[s];
        if ((mask >> lane) & 1ull) {
            const int pos = segoff[s] + __popcll(mask & ((1ull << lane) - 1ull));
            indws[b * FT + pos] = t;
            out[O_IND + (size_t)b * FT + pos] = (float)t;
        }
    }
    if (b == 0 && tid == 0 && write_ft) out[O_FT] = (float)FT;
}

// K_bcast: unchanged.
__global__ __launch_bounds__(256) void k_bcast(const int* __restrict__ ind,
                                               const float* __restrict__ x,
                                               float* __restrict__ out) {
    const float4* x4 = (const float4*)x;
    float4* o4 = (float4*)(out + O_X);
    float4* i4 = (float4*)(out + O_INDEX);
    const unsigned stride = gridDim.x * 256u;
    for (unsigned g = blockIdx.x * 256u + threadIdx.x; g < NIDX4 + NCOPY4; g += stride) {
        if (g < NCOPY4) {
            o4[g] = x4[g];
        } else {
            const unsigned e = g - NCOPY4;
            const unsigned row = e / 192u;       // 192 float4 per 768-float row
            const float v = (float)ind[row];
            float4 o; o.x = v; o.y = v; o.z = v; o.w = v;
            i4[e] = o;
        }
    }
}

extern "C" void kernel_launch(void* const* d_in, const int* in_sizes, int n_in,
                              void* d_out, int out_size, void* d_ws, size_t ws_size,
                              hipStream_t stream) {
    const float* x  = (const float*)d_in[0];
    const float* W  = (const float*)d_in[2];   // W_qkv [768, 2304]
    const float* bq = (const float*)d_in[3];   // b_qkv [2304]
    float* ws = (float*)d_ws;
    float* out = (float*)d_out;

    k_fold<<<dim3(BATCH, HEADS), 512, 0, stream>>>(x, W, bq, ws + WS_WTIL, ws + WS_DBIAS);
    k_dots<<<dim3(BATCH, 10), 256, 0, stream>>>(x, ws + WS_WTIL, ws + WS_DBIAS,
                                                ws + WS_DOTS);
    const int write_ft = (out_size > (int)O_FT) ? 1 : 0;
    k_catopk<<<BATCH, 512, 0, stream>>>(ws + WS_DOTS, out, (int*)(ws + WS_IND), write_ft);
    k_bcast<<<2048, 256, 0, stream>>>((const int*)(ws + WS_IND), x, out);
}